// Round 7
// baseline (330.311 us; speedup 1.0000x reference)
//
#include <hip/hip_runtime.h>
#include <hip/hip_bf16.h>

// GQA block: x@Wqkv -> RoPE -> causal GQA attention -> @Wo
// B=2 T=2048 C=2048 H=16 KV=4 D=128, fp32 in/out, bf16 MFMA internally.

typedef unsigned short u16;
typedef __attribute__((ext_vector_type(8))) short   bf8_t;  // 8 bf16 (MFMA A/B frag)
typedef __attribute__((ext_vector_type(4))) float   f4_t;   // MFMA C/D frag
typedef __attribute__((ext_vector_type(4))) int     i4_t;   // 16B staging reg
typedef __attribute__((ext_vector_type(4))) u16     u16x4;

static constexpr int cB = 2, cT = 2048, cC = 2048, cH = 16, cKV = 4, cD = 128;
static constexpr int cBT = cB * cT;              // 4096 rows
static constexpr int cNQKV = cH*cD + 2*cKV*cD;   // 3072 (Q|K|V)
static constexpr int cKOFF = cH*cD;              // 2048
static constexpr int cVOFF = cH*cD + cKV*cD;     // 2560
static constexpr float cQSCALE = 0.08838834764831843f; // 1/sqrt(128)

#define DEVI __device__ __forceinline__

// global_load_lds address-space casts, via integers (always-legal casts):
// generic->AS1 is numerically identity; generic LDS ptr's low 32 bits = LDS
// byte offset (AMDGPU generic layout). readfirstlane puts LDS base in SGPR
// (CK amd_direct_load pattern).
#define AS1G(p) ((const __attribute__((address_space(1))) void*)(unsigned long long)(p))
#define AS3I(x) ((__attribute__((address_space(3))) void*)(unsigned)(x))

DEVI u16 f2b(float f) {           // fp32 -> bf16 RNE
  union { float f; unsigned u; } v; v.f = f;
  unsigned r = v.u + 0x7FFFu + ((v.u >> 16) & 1u);
  return (u16)(r >> 16);
}
DEVI float b2f(u16 h) {
  union { unsigned u; float f; } v; v.u = ((unsigned)h) << 16; return v.f;
}
DEVI f4_t mfma16(bf8_t a, bf8_t b, f4_t c) {
  return __builtin_amdgcn_mfma_f32_16x16x32_bf16(a, b, c, 0, 0, 0);
}

// ---------------- glue kernels ----------------

__global__ void k_cvt_x(const float* __restrict__ x, u16* __restrict__ xb) {
  int i = (blockIdx.x * 256 + threadIdx.x) * 4;
  float4 v = *(const float4*)(x + i);
  u16x4 o; o.x = f2b(v.x); o.y = f2b(v.y); o.z = f2b(v.z); o.w = f2b(v.w);
  *(u16x4*)(xb + i) = o;
}

// dst[n][k] = src(k, n) as bf16; src split across up to 3 arrays along n.
__global__ void k_tconv(const float* __restrict__ s0, int ld0, int ncut0,
                        const float* __restrict__ s1, int ld1, int ncut1,
                        const float* __restrict__ s2, int ld2,
                        u16* __restrict__ dst, int Kdim) {
  __shared__ float tile[64][65];
  int n0 = blockIdx.x * 64, k0 = blockIdx.y * 64;
  int tid = threadIdx.x;
#pragma unroll
  for (int r = 0; r < 16; ++r) {
    int idx = r * 256 + tid;
    int kk = idx >> 6, nn = idx & 63;
    int n = n0 + nn;
    float v;
    if (n < ncut0)      v = s0[(size_t)(k0 + kk) * ld0 + n];
    else if (n < ncut1) v = s1[(size_t)(k0 + kk) * ld1 + (n - ncut0)];
    else                v = s2[(size_t)(k0 + kk) * ld2 + (n - ncut1)];
    tile[kk][nn] = v;
  }
  __syncthreads();
#pragma unroll
  for (int r = 0; r < 16; ++r) {
    int idx = r * 256 + tid;
    int nn = idx >> 6, kk = idx & 63;
    dst[(size_t)(n0 + nn) * Kdim + k0 + kk] = f2b(tile[kk][nn]);
  }
}

__global__ void k_ropetab(float* __restrict__ cosb, float* __restrict__ sinb) {
  int i = blockIdx.x * 256 + threadIdx.x;  // T*64
  int t = i >> 6, d = i & 63;
  float th = powf(10000.f, -(float)d / 64.f);
  float f = (float)t * th;
  cosb[i] = cosf(f);
  sinb[i] = sinf(f);
}

// in-place RoPE on bf16 qkv rows; heads 0..15 = Q (also *scale), 16..19 = K.
// Vectorized: one thread = 4 (lo,hi) pairs.
__global__ void k_rope(u16* __restrict__ qkv, const float* __restrict__ cosb,
                       const float* __restrict__ sinb) {
  int i = blockIdx.x * 256 + threadIdx.x;      // BT * 20 heads * 16 quads
  int row = i / 320, p = i - row * 320;
  int head = p >> 4, d4 = (p & 15) << 2;       // d = d4 .. d4+3 (of 64)
  int t = row & (cT - 1);
  u16* base = qkv + (size_t)row * cNQKV + head * cD + d4;
  u16x4 lo4 = *(u16x4*)base;
  u16x4 hi4 = *(u16x4*)(base + 64);
  float4 cv = *(const float4*)(cosb + (t << 6) + d4);
  float4 sv = *(const float4*)(sinb + (t << 6) + d4);
  float sc = (head < cH) ? cQSCALE : 1.f;
  u16x4 olo, ohi;
#pragma unroll
  for (int j = 0; j < 4; ++j) {
    float lo = b2f(lo4[j]), hi = b2f(hi4[j]);
    float c = (&cv.x)[j], s = (&sv.x)[j];
    olo[j] = f2b((lo * c - hi * s) * sc);
    ohi[j] = f2b((hi * c + lo * s) * sc);
  }
  *(u16x4*)base = olo;
  *(u16x4*)(base + 64) = ohi;
}

// vt[b,g,d,t] = V[b,t,g,d]  (64x64 LDS tile transpose)
__global__ void k_vtrans(const u16* __restrict__ qkv, u16* __restrict__ vt) {
  __shared__ u16 tile[64][65];
  int s0 = blockIdx.x * 64, d0 = blockIdx.y * 64, bg = blockIdx.z;
  int b = bg >> 2, g = bg & 3;
  int tid = threadIdx.x;
#pragma unroll
  for (int r = 0; r < 16; ++r) {
    int idx = r * 256 + tid;
    int ss = idx >> 6, dd = idx & 63;
    tile[ss][dd] = qkv[(size_t)(b * cT + s0 + ss) * cNQKV + cVOFF + g * cD + d0 + dd];
  }
  __syncthreads();
#pragma unroll
  for (int r = 0; r < 16; ++r) {
    int idx = r * 256 + tid;
    int dd = idx >> 6, ss = idx & 63;
    vt[(size_t)((b * cKV + g) * cD + d0 + dd) * cT + s0 + ss] = tile[ss][dd];
  }
}

// ---------------- GEMM: C(M x N_) = A(M x K) * Bt(N_ x K)^T ----------------
// m97 structure: 128x128 tile, BK=32, 4 waves (2x2), 16x16x32 bf16 MFMA,
// global_load_lds width-16 direct-to-LDS staging (no VGPR round trip).
// Thread tid's LDS slot = bytes [tid*16, tid*16+16) = wave base w*1024 +
// lane*16 (the linear form global_load_lds requires); global src is per-lane.
template <int N_, bool OUTF32>
__global__ __launch_bounds__(256) void k_gemm_bt(const u16* __restrict__ A,
                                                 const u16* __restrict__ Bt,
                                                 void* __restrict__ Cout) {
  constexpr int K_ = 2048;
  __shared__ __align__(16) u16 As[128 * 32];
  __shared__ __align__(16) u16 Bs[128 * 32];
  int tid = threadIdx.x;
  int l = tid & 63;
  int w = tid >> 6;
  int l15 = l & 15, l4 = l >> 4;
  int wm = w >> 1, wn = w & 1;
  int m0 = blockIdx.y * 128, n0 = blockIdx.x * 128;

  // staging: thread t covers rows (t/4, t/4+64), 16B at kbyte (t%4)*16
  int srow = tid >> 2;
  int kby = (tid & 3) * 16;
  const char* aG = (const char*)A  + ((size_t)(m0 + srow) * K_) * 2 + kby;
  const char* bG = (const char*)Bt + ((size_t)(n0 + srow) * K_) * 2 + kby;
  const size_t rstride = (size_t)64 * K_ * 2;  // +64 rows

  // wave-uniform LDS base offsets (SGPR via readfirstlane; CK pattern)
  unsigned asB = __builtin_amdgcn_readfirstlane(
      (unsigned)(unsigned long long)(const char*)As + (unsigned)w * 1024u);
  unsigned bsB = __builtin_amdgcn_readfirstlane(
      (unsigned)(unsigned long long)(const char*)Bs + (unsigned)w * 1024u);

  f4_t acc[4][4];
  f4_t zf = {0.f, 0.f, 0.f, 0.f};
#pragma unroll
  for (int m = 0; m < 4; ++m)
#pragma unroll
    for (int n = 0; n < 4; ++n) acc[m][n] = zf;

  for (int ks = 0; ks < K_ / 32; ++ks) {
    const char* aN = aG + (size_t)ks * 64;
    const char* bN = bG + (size_t)ks * 64;
    __builtin_amdgcn_global_load_lds(AS1G(aN),            AS3I(asB),        16, 0, 0);
    __builtin_amdgcn_global_load_lds(AS1G(aN + rstride),  AS3I(asB + 4096), 16, 0, 0);
    __builtin_amdgcn_global_load_lds(AS1G(bN),            AS3I(bsB),        16, 0, 0);
    __builtin_amdgcn_global_load_lds(AS1G(bN + rstride),  AS3I(bsB + 4096), 16, 0, 0);
    __syncthreads();  // compiler drains vmcnt(0) here: tiles resident

    bf8_t af[4], bfr[4];
#pragma unroll
    for (int m = 0; m < 4; ++m)
      af[m] = *(const bf8_t*)&As[(wm * 64 + m * 16 + l15) * 32 + l4 * 8];
#pragma unroll
    for (int n = 0; n < 4; ++n)
      bfr[n] = *(const bf8_t*)&Bs[(wn * 64 + n * 16 + l15) * 32 + l4 * 8];
#pragma unroll
    for (int m = 0; m < 4; ++m)
#pragma unroll
      for (int n = 0; n < 4; ++n)
        acc[m][n] = mfma16(af[m], bfr[n], acc[m][n]);
    __syncthreads();  // protect LDS before next iteration's DMA writes
  }
  // epilogue: D row=(l>>4)*4+r, col=l&15  [m89-verified]
#pragma unroll
  for (int m = 0; m < 4; ++m) {
#pragma unroll
    for (int n = 0; n < 4; ++n) {
      int col = n0 + wn * 64 + n * 16 + l15;
#pragma unroll
      for (int r = 0; r < 4; ++r) {
        int row = m0 + wm * 64 + m * 16 + l4 * 4 + r;
        if (OUTF32)
          ((float*)Cout)[(size_t)row * N_ + col] = acc[m][n][r];
        else
          ((u16*)Cout)[(size_t)row * N_ + col] = f2b(acc[m][n][r]);
      }
    }
  }
}

// ---------------- fused causal GQA attention ----------------
// LPT dispatch for causal imbalance: 1024 one-tile blocks, qt = 31 - blockIdx.y
// so the longest blocks (qt=31) dispatch FIRST and short blocks backfill.
// LDS = 16K(Kl) + 16K(Vl) + 8K(Pl) = 40960 B exactly -> 4 blocks/CU
// (VGPR 124 <= 128 allows 16 waves/CU). 4 waves x 16 q-rows; KV tiles of 64.
// K LDS [64][128], V LDS [128][64] (pre-transposed vt), and Pl [16][64] all
// XOR-swizzled (byte ^= (row&7)<<4) per G4 — swizzle replaces Pl's old +8 pad.
__global__ __launch_bounds__(256) void k_attn(const u16* __restrict__ qkv,
                                              const u16* __restrict__ vt,
                                              u16* __restrict__ obuf) {
  __shared__ __align__(16) u16 Kl[64 * 128];
  __shared__ __align__(16) u16 Vl[128 * 64];
  __shared__ __align__(16) u16 Pl[4][16 * 64];  // per-wave P buffer, swizzled

  int bh = blockIdx.x;               // fast dim: all (b,h) at one qt-level
  int qt = 31 - (int)blockIdx.y;     // slow dim: descending work (LPT)
  int b = bh >> 4, h = bh & 15;
  int g = h >> 2;  // kv head (R=4)
  int tid = threadIdx.x;
  int l = tid & 63, w = tid >> 6;
  int l15 = l & 15, l4 = l >> 4;

  const char* qkvB = (const char*)qkv;
  const char* vtB  = (const char*)vt;
  const size_t kRowBase = ((size_t)(b * cT) * cNQKV + cKOFF + g * cD) * 2;
  const size_t vRowBase = ((size_t)((b * cKV + g) * cD)) * cT * 2;
  f4_t zf = {0.f, 0.f, 0.f, 0.f};

  // Q fragments in registers (A-operand: row=l&15, k=(l>>4)*8+j)
  int trow = qt * 64 + w * 16 + l15;
  const u16* qrow = qkv + (size_t)(b * cT + trow) * cNQKV + h * cD;
  bf8_t qf[4];
#pragma unroll
  for (int kc = 0; kc < 4; ++kc) qf[kc] = *(const bf8_t*)(qrow + kc * 32 + l4 * 8);

  f4_t occ[8];
#pragma unroll
  for (int c = 0; c < 8; ++c) occ[c] = zf;
  float mrun[4], lrun[4];
#pragma unroll
  for (int r = 0; r < 4; ++r) { mrun[r] = -__builtin_inff(); lrun[r] = 0.f; }

  i4_t kreg[4], vreg[4];
#pragma unroll
  for (int rr = 0; rr < 4; ++rr) {  // prologue: tile 0 -> regs
    int off = tid * 16 + rr * 4096;
    int s = off >> 8, dby = off & 255;
    kreg[rr] = *(const i4_t*)(qkvB + kRowBase + (size_t)s * (cNQKV * 2) + dby);
    int dv = off >> 7, sby = off & 127;
    vreg[rr] = *(const i4_t*)(vtB + vRowBase + (size_t)dv * (cT * 2) + sby);
  }

  int nt = qt + 1;  // causal tile bound
  for (int it = 0; it < nt; ++it) {
#pragma unroll
    for (int rr = 0; rr < 4; ++rr) {  // regs -> LDS (swizzled)
      int off = tid * 16 + rr * 4096;
      int s = off >> 8, dby = off & 255;
      *(i4_t*)((char*)Kl + (((s << 8) + dby) ^ ((s & 7) << 4))) = kreg[rr];
      int dv = off >> 7, sby = off & 127;
      *(i4_t*)((char*)Vl + (((dv << 7) + sby) ^ ((dv & 7) << 4))) = vreg[rr];
    }
    __syncthreads();
    if (it + 1 < nt) {  // prefetch next tile into regs (hidden under MFMA)
      int s0n = (it + 1) * 64;
#pragma unroll
      for (int rr = 0; rr < 4; ++rr) {
        int off = tid * 16 + rr * 4096;
        int s = off >> 8, dby = off & 255;
        kreg[rr] = *(const i4_t*)(qkvB + kRowBase + (size_t)(s0n + s) * (cNQKV * 2) + dby);
        int dv = off >> 7, sby = off & 127;
        vreg[rr] = *(const i4_t*)(vtB + vRowBase + (size_t)dv * (cT * 2) + (size_t)s0n * 2 + sby);
      }
    }
    // S = Q K^T  (16 q-rows x 64 kv-cols per wave)
    f4_t sac[4];
#pragma unroll
    for (int ct = 0; ct < 4; ++ct) sac[ct] = zf;
    __builtin_amdgcn_s_setprio(1);
#pragma unroll
    for (int ct = 0; ct < 4; ++ct) {
      int srow = ct * 16 + l15;
#pragma unroll
      for (int kc = 0; kc < 4; ++kc) {
        bf8_t kf = *(const bf8_t*)((const char*)Kl +
                   (((srow << 8) + (kc << 6) + (l4 << 4)) ^ ((srow & 7) << 4)));
        sac[ct] = mfma16(qf[kc], kf, sac[ct]);
      }
    }
    __builtin_amdgcn_s_setprio(0);
    // online softmax; lane holds rows l4*4+r, cols ct*16+l15.
    // Masking needed only on the diagonal tile (it==qt) — uniform branch.
    float p[4][4], fac[4];
    if (it < qt) {  // full tile, no mask
#pragma unroll
      for (int r = 0; r < 4; ++r) {
        float mx = fmaxf(fmaxf(sac[0][r], sac[1][r]), fmaxf(sac[2][r], sac[3][r]));
        mx = fmaxf(mx, __shfl_xor(mx, 1));
        mx = fmaxf(mx, __shfl_xor(mx, 2));
        mx = fmaxf(mx, __shfl_xor(mx, 4));
        mx = fmaxf(mx, __shfl_xor(mx, 8));
        float mnew = fmaxf(mrun[r], mx);
        fac[r] = __expf(mrun[r] - mnew);
        mrun[r] = mnew;
        float ps = 0.f;
#pragma unroll
        for (int ct = 0; ct < 4; ++ct) {
          float pv = __expf(sac[ct][r] - mnew);
          p[ct][r] = pv;
          ps += pv;
        }
        ps += __shfl_xor(ps, 1);
        ps += __shfl_xor(ps, 2);
        ps += __shfl_xor(ps, 4);
        ps += __shfl_xor(ps, 8);
        lrun[r] = lrun[r] * fac[r] + ps;
      }
    } else {  // diagonal tile: causal mask
      int s0 = it * 64;
#pragma unroll
      for (int r = 0; r < 4; ++r) {
        int tg = qt * 64 + w * 16 + l4 * 4 + r;
        float mx = -__builtin_inff();
#pragma unroll
        for (int ct = 0; ct < 4; ++ct) {
          int sg = s0 + ct * 16 + l15;
          float sv = (sg <= tg) ? sac[ct][r] : -__builtin_inff();
          mx = fmaxf(mx, sv);
        }
        mx = fmaxf(mx, __shfl_xor(mx, 1));
        mx = fmaxf(mx, __shfl_xor(mx, 2));
        mx = fmaxf(mx, __shfl_xor(mx, 4));
        mx = fmaxf(mx, __shfl_xor(mx, 8));
        float mnew = fmaxf(mrun[r], mx);
        fac[r] = __expf(mrun[r] - mnew);
        mrun[r] = mnew;
        float ps = 0.f;
#pragma unroll
        for (int ct = 0; ct < 4; ++ct) {
          int sg = s0 + ct * 16 + l15;
          float pv = (sg <= tg) ? __expf(sac[ct][r] - mnew) : 0.f;
          p[ct][r] = pv;
          ps += pv;
        }
        ps += __shfl_xor(ps, 1);
        ps += __shfl_xor(ps, 2);
        ps += __shfl_xor(ps, 4);
        ps += __shfl_xor(ps, 8);
        lrun[r] = lrun[r] * fac[r] + ps;
      }
    }
#pragma unroll
    for (int c = 0; c < 8; ++c)
#pragma unroll
      for (int r = 0; r < 4; ++r) occ[c][r] *= fac[r];
    // P (D-layout) -> LDS (swizzled rows) -> A-layout for PV
#pragma unroll
    for (int ct = 0; ct < 4; ++ct)
#pragma unroll
      for (int r = 0; r < 4; ++r) {
        int prow = l4 * 4 + r, pcol = ct * 16 + l15;
        unsigned pby = (unsigned)((prow << 7) + (pcol << 1));
        *(u16*)((char*)&Pl[w][0] + (pby ^ ((prow & 7) << 4))) = f2b(p[ct][r]);
      }
    // cross-lane LDS RAW within the wave: drain LDS queue before reading P
    asm volatile("s_waitcnt lgkmcnt(0)" ::: "memory");
    __builtin_amdgcn_sched_barrier(0);
    __builtin_amdgcn_s_setprio(1);
#pragma unroll
    for (int kc2 = 0; kc2 < 2; ++kc2) {
      unsigned rby = (unsigned)((l15 << 7) + (kc2 << 6) + (l4 << 4));
      bf8_t pf = *(const bf8_t*)((const char*)&Pl[w][0] + (rby ^ ((l15 & 7) << 4)));
#pragma unroll
      for (int c = 0; c < 8; ++c) {
        int drow = c * 16 + l15;
        bf8_t vf = *(const bf8_t*)((const char*)Vl +
                   (((drow << 7) + (kc2 << 6) + (l4 << 4)) ^ ((drow & 7) << 4)));
        occ[c] = mfma16(pf, vf, occ[c]);
      }
    }
    __builtin_amdgcn_s_setprio(0);
    __syncthreads();
  }
  // epilogue: O /= l, write bf16 (B*T, H*D)
  float inv[4];
#pragma unroll
  for (int r = 0; r < 4; ++r) inv[r] = 1.f / lrun[r];
  int orow0 = qt * 64 + w * 16 + l4 * 4;
#pragma unroll
  for (int c = 0; c < 8; ++c) {
    int col = h * cD + c * 16 + l15;
#pragma unroll
    for (int r = 0; r < 4; ++r)
      obuf[(size_t)(b * cT + orow0 + r) * (cH * cD) + col] = f2b(occ[c][r] * inv[r]);
  }
}

// ---------------- launch ----------------

extern "C" void kernel_launch(void* const* d_in, const int* in_sizes, int n_in,
                              void* d_out, int out_size, void* d_ws, size_t ws_size,
                              hipStream_t stream) {
  (void)in_sizes; (void)n_in; (void)out_size; (void)ws_size;
  const float* x  = (const float*)d_in[0];
  const float* Wq = (const float*)d_in[1];
  const float* Wk = (const float*)d_in[2];
  const float* Wv = (const float*)d_in[3];
  const float* Wo = (const float*)d_in[4];

  char* p = (char*)d_ws;
  u16* xb   = (u16*)p;  p += (size_t)cBT * cC * 2;        // 16.8 MB (reused as ob)
  u16* wt   = (u16*)p;  p += (size_t)cNQKV * cC * 2;      // 12.6 MB (Wqkv^T)
  u16* wot  = (u16*)p;  p += (size_t)cC * cC * 2;         // 8.4 MB  (Wo^T)
  u16* qkv  = (u16*)p;  p += (size_t)cBT * cNQKV * 2;     // 25.2 MB
  u16* vt   = (u16*)p;  p += (size_t)cB * cKV * cD * cT * 2; // 4.2 MB
  float* cosb = (float*)p; p += (size_t)cT * 64 * 4;      // 0.5 MB
  float* sinb = (float*)p; p += (size_t)cT * 64 * 4;      // 0.5 MB
  u16* ob = xb;  // xb dead after QKV GEMM; ob born in k_attn — lifetimes disjoint

  k_cvt_x<<<dim3(cBT * cC / 1024), 256, 0, stream>>>(x, xb);
  k_tconv<<<dim3(cNQKV / 64, cC / 64), 256, 0, stream>>>(
      Wq, cH * cD, cH * cD, Wk, cKV * cD, cH * cD + cKV * cD, Wv, cKV * cD, wt, cC);
  k_tconv<<<dim3(cC / 64, cC / 64), 256, 0, stream>>>(
      Wo, cC, cC, Wo, cC, cC, Wo, cC, wot, cC);
  k_ropetab<<<dim3(cT * 64 / 256), 256, 0, stream>>>(cosb, sinb);
  k_gemm_bt<cNQKV, false><<<dim3(cNQKV / 128, cBT / 128), 256, 0, stream>>>(xb, wt, qkv);
  k_rope<<<dim3(cBT * 320 / 256), 256, 0, stream>>>(qkv, cosb, sinb);
  k_vtrans<<<dim3(cT / 64, cD / 64, cB * cKV), 256, 0, stream>>>(qkv, vt);
  // LPT: x = (b,h) fast, y = descending qt (longest blocks dispatch first)
  k_attn<<<dim3(cB * cH, cT / 64), 256, 0, stream>>>(qkv, vt, ob);
  k_gemm_bt<cC, true><<<dim3(cC / 128, cBT / 128), 256, 0, stream>>>(ob, wot, d_out);
}

// Round 8
// 325.032 us; speedup vs baseline: 1.0162x; 1.0162x over previous
//
#include <hip/hip_runtime.h>
#include <hip/hip_bf16.h>

// GQA block: x@Wqkv -> RoPE -> causal GQA attention -> @Wo
// B=2 T=2048 C=2048 H=16 KV=4 D=128, fp32 in/out, bf16 MFMA internally.

typedef unsigned short u16;
typedef __attribute__((ext_vector_type(8))) short   bf8_t;  // 8 bf16 (MFMA A/B frag)
typedef __attribute__((ext_vector_type(4))) float   f4_t;   // MFMA C/D frag
typedef __attribute__((ext_vector_type(4))) int     i4_t;   // 16B staging reg
typedef __attribute__((ext_vector_type(4))) u16     u16x4;

static constexpr int cB = 2, cT = 2048, cC = 2048, cH = 16, cKV = 4, cD = 128;
static constexpr int cBT = cB * cT;              // 4096 rows
static constexpr int cNQKV = cH*cD + 2*cKV*cD;   // 3072 (Q|K|V)
static constexpr int cKOFF = cH*cD;              // 2048
static constexpr int cVOFF = cH*cD + cKV*cD;     // 2560
static constexpr float cQSCALE = 0.08838834764831843f; // 1/sqrt(128)

#define DEVI __device__ __forceinline__

// global_load_lds address-space casts, via integers (always-legal casts):
// generic->AS1 is numerically identity; generic LDS ptr's low 32 bits = LDS
// byte offset. readfirstlane puts LDS base in SGPR (CK amd_direct_load).
#define AS1G(p) ((const __attribute__((address_space(1))) void*)(unsigned long long)(p))
#define AS3I(x) ((__attribute__((address_space(3))) void*)(unsigned)(x))

DEVI u16 f2b(float f) {           // fp32 -> bf16 RNE
  union { float f; unsigned u; } v; v.f = f;
  unsigned r = v.u + 0x7FFFu + ((v.u >> 16) & 1u);
  return (u16)(r >> 16);
}
DEVI float b2f(u16 h) {
  union { unsigned u; float f; } v; v.u = ((unsigned)h) << 16; return v.f;
}
DEVI f4_t mfma16(bf8_t a, bf8_t b, f4_t c) {
  return __builtin_amdgcn_mfma_f32_16x16x32_bf16(a, b, c, 0, 0, 0);
}

// ---------------- glue kernels ----------------

__global__ void k_cvt_x(const float* __restrict__ x, u16* __restrict__ xb) {
  int i = (blockIdx.x * 256 + threadIdx.x) * 4;
  float4 v = *(const float4*)(x + i);
  u16x4 o; o.x = f2b(v.x); o.y = f2b(v.y); o.z = f2b(v.z); o.w = f2b(v.w);
  *(u16x4*)(xb + i) = o;
}

// dst[n][k] = src(k, n) as bf16; src split across up to 3 arrays along n.
__global__ void k_tconv(const float* __restrict__ s0, int ld0, int ncut0,
                        const float* __restrict__ s1, int ld1, int ncut1,
                        const float* __restrict__ s2, int ld2,
                        u16* __restrict__ dst, int Kdim) {
  __shared__ float tile[64][65];
  int n0 = blockIdx.x * 64, k0 = blockIdx.y * 64;
  int tid = threadIdx.x;
#pragma unroll
  for (int r = 0; r < 16; ++r) {
    int idx = r * 256 + tid;
    int kk = idx >> 6, nn = idx & 63;
    int n = n0 + nn;
    float v;
    if (n < ncut0)      v = s0[(size_t)(k0 + kk) * ld0 + n];
    else if (n < ncut1) v = s1[(size_t)(k0 + kk) * ld1 + (n - ncut0)];
    else                v = s2[(size_t)(k0 + kk) * ld2 + (n - ncut1)];
    tile[kk][nn] = v;
  }
  __syncthreads();
#pragma unroll
  for (int r = 0; r < 16; ++r) {
    int idx = r * 256 + tid;
    int nn = idx >> 6, kk = idx & 63;
    dst[(size_t)(n0 + nn) * Kdim + k0 + kk] = f2b(tile[kk][nn]);
  }
}

__global__ void k_ropetab(float* __restrict__ cosb, float* __restrict__ sinb) {
  int i = blockIdx.x * 256 + threadIdx.x;  // T*64
  int t = i >> 6, d = i & 63;
  float th = powf(10000.f, -(float)d / 64.f);
  float f = (float)t * th;
  cosb[i] = cosf(f);
  sinb[i] = sinf(f);
}

// in-place RoPE on bf16 qkv rows; heads 0..15 = Q (also *scale), 16..19 = K.
__global__ void k_rope(u16* __restrict__ qkv, const float* __restrict__ cosb,
                       const float* __restrict__ sinb) {
  int i = blockIdx.x * 256 + threadIdx.x;      // BT * 20 heads * 16 quads
  int row = i / 320, p = i - row * 320;
  int head = p >> 4, d4 = (p & 15) << 2;       // d = d4 .. d4+3 (of 64)
  int t = row & (cT - 1);
  u16* base = qkv + (size_t)row * cNQKV + head * cD + d4;
  u16x4 lo4 = *(u16x4*)base;
  u16x4 hi4 = *(u16x4*)(base + 64);
  float4 cv = *(const float4*)(cosb + (t << 6) + d4);
  float4 sv = *(const float4*)(sinb + (t << 6) + d4);
  float sc = (head < cH) ? cQSCALE : 1.f;
  u16x4 olo, ohi;
#pragma unroll
  for (int j = 0; j < 4; ++j) {
    float lo = b2f(lo4[j]), hi = b2f(hi4[j]);
    float c = (&cv.x)[j], s = (&sv.x)[j];
    olo[j] = f2b((lo * c - hi * s) * sc);
    ohi[j] = f2b((hi * c + lo * s) * sc);
  }
  *(u16x4*)base = olo;
  *(u16x4*)(base + 64) = ohi;
}

// vt[b,g,d,t] = V[b,t,g,d]  (64x64 LDS tile transpose)
__global__ void k_vtrans(const u16* __restrict__ qkv, u16* __restrict__ vt) {
  __shared__ u16 tile[64][65];
  int s0 = blockIdx.x * 64, d0 = blockIdx.y * 64, bg = blockIdx.z;
  int b = bg >> 2, g = bg & 3;
  int tid = threadIdx.x;
#pragma unroll
  for (int r = 0; r < 16; ++r) {
    int idx = r * 256 + tid;
    int ss = idx >> 6, dd = idx & 63;
    tile[ss][dd] = qkv[(size_t)(b * cT + s0 + ss) * cNQKV + cVOFF + g * cD + d0 + dd];
  }
  __syncthreads();
#pragma unroll
  for (int r = 0; r < 16; ++r) {
    int idx = r * 256 + tid;
    int dd = idx >> 6, ss = idx & 63;
    vt[(size_t)((b * cKV + g) * cD + d0 + dd) * cT + s0 + ss] = tile[ss][dd];
  }
}

// ---------------- GEMM: C(M x N_) = A(M x K) * Bt(N_ x K)^T ----------------
// 128x256 tile, BK=32, 8 waves (2x4), ring of 4 LDS slots (96 KB), counted
// vmcnt (T3/T4): one raw s_barrier + vmcnt(6) per K-step, loads stay in
// flight across barriers (no vmcnt(0) drain in steady state).
// Slot layout: A[128 rows x 64B] @ +0, B[256 rows x 64B] @ +8192; row's four
// 16B k-slots XOR-swizzled by ((row>>1)&3)<<4 on BOTH global source and LDS
// read (involution; gload_lds dest stays linear: byte = chunk*16).
// Safety: tile kt+3 -> slot (kt+3)&3 whose last readers (iter kt-1) finished
// before barrier(kt) (reads complete before MFMA, MFMA precedes barrier);
// vmcnt(6)+barrier => tile kt resident for all waves before reads.
template <int NBLK, bool OUTF32>
__global__ __launch_bounds__(512, 2) void k_gemm256(const u16* __restrict__ A,
                                                    const u16* __restrict__ Bt,
                                                    void* __restrict__ Cout) {
  constexpr int K_ = 2048, NT = K_ / 32;
  __shared__ __align__(16) u16 lds[4 * 12288];   // 4 slots x 24576 B = 96 KB
  const int tid = threadIdx.x;
  const int l = tid & 63, wid = tid >> 6;
  const int l15 = l & 15, l4 = l >> 4;
  const int wr = wid >> 2, wc = wid & 3;         // wave tile: rows wr*64, cols wc*64
  const int m0 = blockIdx.y * 128, n0 = blockIdx.x * 256;

  // staging source: chunk tid -> row tid>>2, k-slot tid&3 (source pre-swizzled)
  const int rowS = tid >> 2, slotS = tid & 3;
  const int colS = (slotS * 16) ^ (((rowS >> 1) & 3) << 4);
  const char* aG  = (const char*)A  + ((size_t)(m0 + rowS) * K_) * 2 + colS;
  const char* bG0 = (const char*)Bt + ((size_t)(n0 + rowS) * K_) * 2 + colS;
  const char* bG1 = (const char*)Bt + ((size_t)(n0 + 128 + rowS) * K_) * 2 + colS;
  // ((rowS+128)>>1)&3 == (rowS>>1)&3, so bG1 shares colS.

  // wave-uniform LDS dest bases (lane*16 added by HW)
  const unsigned ldsB = (unsigned)(unsigned long long)(const char*)lds;
  const unsigned aDst  = __builtin_amdgcn_readfirstlane(ldsB + (unsigned)wid * 1024u);
  const unsigned bDst0 = __builtin_amdgcn_readfirstlane(ldsB + 8192u + (unsigned)wid * 1024u);
  const unsigned bDst1 = __builtin_amdgcn_readfirstlane(ldsB + 16384u + (unsigned)wid * 1024u);

#define G_STAGE(kt_) { \
    const unsigned sb_ = (unsigned)((kt_) & 3) * 24576u; \
    __builtin_amdgcn_global_load_lds(AS1G(aG  + (size_t)(kt_) * 64), AS3I(aDst  + sb_), 16, 0, 0); \
    __builtin_amdgcn_global_load_lds(AS1G(bG0 + (size_t)(kt_) * 64), AS3I(bDst0 + sb_), 16, 0, 0); \
    __builtin_amdgcn_global_load_lds(AS1G(bG1 + (size_t)(kt_) * 64), AS3I(bDst1 + sb_), 16, 0, 0); }

  f4_t acc[4][4];
  f4_t zf = {0.f, 0.f, 0.f, 0.f};
#pragma unroll
  for (int m = 0; m < 4; ++m)
#pragma unroll
    for (int n = 0; n < 4; ++n) acc[m][n] = zf;

  // prologue: 3 tiles in flight (9 loads/thread)
  G_STAGE(0); G_STAGE(1); G_STAGE(2);

  for (int kt = 0; kt < NT; ++kt) {
    // wait until tile kt's loads (this thread's 3 chunks) are resident;
    // allow the 2 younger tiles (6 loads) to stay in flight.
    if (kt < NT - 2)       asm volatile("s_waitcnt vmcnt(6)" ::: "memory");
    else if (kt == NT - 2) asm volatile("s_waitcnt vmcnt(3)" ::: "memory");
    else                   asm volatile("s_waitcnt vmcnt(0)" ::: "memory");
    __builtin_amdgcn_s_barrier();        // all waves' tile-kt chunks resident
    __builtin_amdgcn_sched_barrier(0);
    if (kt + 3 < NT) G_STAGE(kt + 3);    // into slot (kt+3)&3 = last iter's slot

    const unsigned sb = (unsigned)(kt & 3) * 24576u;
    bf8_t af[4], bf[4];
#pragma unroll
    for (int m = 0; m < 4; ++m) {
      int row = wr * 64 + m * 16 + l15;
      af[m] = *(const bf8_t*)((const char*)lds + sb + row * 64 +
                              ((l4 * 16) ^ (((row >> 1) & 3) << 4)));
    }
#pragma unroll
    for (int n = 0; n < 4; ++n) {
      int row = wc * 64 + n * 16 + l15;
      bf[n] = *(const bf8_t*)((const char*)lds + sb + 8192 + row * 64 +
                              ((l4 * 16) ^ (((row >> 1) & 3) << 4)));
    }
#pragma unroll
    for (int m = 0; m < 4; ++m)
#pragma unroll
      for (int n = 0; n < 4; ++n)
        acc[m][n] = mfma16(af[m], bf[n], acc[m][n]);
  }
#undef G_STAGE
  // epilogue: D row=(l>>4)*4+r, col=l&15  [m89-verified]
#pragma unroll
  for (int m = 0; m < 4; ++m) {
#pragma unroll
    for (int n = 0; n < 4; ++n) {
      int col = n0 + wc * 64 + n * 16 + l15;
#pragma unroll
      for (int r = 0; r < 4; ++r) {
        int row = m0 + wr * 64 + m * 16 + l4 * 4 + r;
        if (OUTF32)
          ((float*)Cout)[(size_t)row * NBLK + col] = acc[m][n][r];
        else
          ((u16*)Cout)[(size_t)row * NBLK + col] = f2b(acc[m][n][r]);
      }
    }
  }
}

// ---------------- fused causal GQA attention ----------------
// LPT dispatch: qt = 31 - blockIdx.y (longest first, short blocks backfill).
// 3 blocks/CU resident. 4 waves x 16 q-rows; KV tiles of 64. K/V/P LDS
// XOR-swizzled (byte ^= (row&7)<<4) per G4. Banked at ~104 us (R5-R7).
__global__ __launch_bounds__(256) void k_attn(const u16* __restrict__ qkv,
                                              const u16* __restrict__ vt,
                                              u16* __restrict__ obuf) {
  __shared__ __align__(16) u16 Kl[64 * 128];
  __shared__ __align__(16) u16 Vl[128 * 64];
  __shared__ __align__(16) u16 Pl[4][16 * 64];  // per-wave P buffer, swizzled

  int bh = blockIdx.x;               // fast dim: all (b,h) at one qt-level
  int qt = 31 - (int)blockIdx.y;     // slow dim: descending work (LPT)
  int b = bh >> 4, h = bh & 15;
  int g = h >> 2;  // kv head (R=4)
  int tid = threadIdx.x;
  int l = tid & 63, w = tid >> 6;
  int l15 = l & 15, l4 = l >> 4;

  const char* qkvB = (const char*)qkv;
  const char* vtB  = (const char*)vt;
  const size_t kRowBase = ((size_t)(b * cT) * cNQKV + cKOFF + g * cD) * 2;
  const size_t vRowBase = ((size_t)((b * cKV + g) * cD)) * cT * 2;
  f4_t zf = {0.f, 0.f, 0.f, 0.f};

  // Q fragments in registers (A-operand: row=l&15, k=(l>>4)*8+j)
  int trow = qt * 64 + w * 16 + l15;
  const u16* qrow = qkv + (size_t)(b * cT + trow) * cNQKV + h * cD;
  bf8_t qf[4];
#pragma unroll
  for (int kc = 0; kc < 4; ++kc) qf[kc] = *(const bf8_t*)(qrow + kc * 32 + l4 * 8);

  f4_t occ[8];
#pragma unroll
  for (int c = 0; c < 8; ++c) occ[c] = zf;
  float mrun[4], lrun[4];
#pragma unroll
  for (int r = 0; r < 4; ++r) { mrun[r] = -__builtin_inff(); lrun[r] = 0.f; }

  i4_t kreg[4], vreg[4];
#pragma unroll
  for (int rr = 0; rr < 4; ++rr) {  // prologue: tile 0 -> regs
    int off = tid * 16 + rr * 4096;
    int s = off >> 8, dby = off & 255;
    kreg[rr] = *(const i4_t*)(qkvB + kRowBase + (size_t)s * (cNQKV * 2) + dby);
    int dv = off >> 7, sby = off & 127;
    vreg[rr] = *(const i4_t*)(vtB + vRowBase + (size_t)dv * (cT * 2) + sby);
  }

  int nt = qt + 1;  // causal tile bound
  for (int it = 0; it < nt; ++it) {
#pragma unroll
    for (int rr = 0; rr < 4; ++rr) {  // regs -> LDS (swizzled)
      int off = tid * 16 + rr * 4096;
      int s = off >> 8, dby = off & 255;
      *(i4_t*)((char*)Kl + (((s << 8) + dby) ^ ((s & 7) << 4))) = kreg[rr];
      int dv = off >> 7, sby = off & 127;
      *(i4_t*)((char*)Vl + (((dv << 7) + sby) ^ ((dv & 7) << 4))) = vreg[rr];
    }
    __syncthreads();
    if (it + 1 < nt) {  // prefetch next tile into regs (hidden under MFMA)
      int s0n = (it + 1) * 64;
#pragma unroll
      for (int rr = 0; rr < 4; ++rr) {
        int off = tid * 16 + rr * 4096;
        int s = off >> 8, dby = off & 255;
        kreg[rr] = *(const i4_t*)(qkvB + kRowBase + (size_t)(s0n + s) * (cNQKV * 2) + dby);
        int dv = off >> 7, sby = off & 127;
        vreg[rr] = *(const i4_t*)(vtB + vRowBase + (size_t)dv * (cT * 2) + (size_t)s0n * 2 + sby);
      }
    }
    // S = Q K^T  (16 q-rows x 64 kv-cols per wave)
    f4_t sac[4];
#pragma unroll
    for (int ct = 0; ct < 4; ++ct) sac[ct] = zf;
    __builtin_amdgcn_s_setprio(1);
#pragma unroll
    for (int ct = 0; ct < 4; ++ct) {
      int srow = ct * 16 + l15;
#pragma unroll
      for (int kc = 0; kc < 4; ++kc) {
        bf8_t kf = *(const bf8_t*)((const char*)Kl +
                   (((srow << 8) + (kc << 6) + (l4 << 4)) ^ ((srow & 7) << 4)));
        sac[ct] = mfma16(qf[kc], kf, sac[ct]);
      }
    }
    __builtin_amdgcn_s_setprio(0);
    // online softmax; lane holds rows l4*4+r, cols ct*16+l15.
    float p[4][4], fac[4];
    if (it < qt) {  // full tile, no mask
#pragma unroll
      for (int r = 0; r < 4; ++r) {
        float mx = fmaxf(fmaxf(sac[0][r], sac[1][r]), fmaxf(sac[2][r], sac[3][r]));
        mx = fmaxf(mx, __shfl_xor(mx, 1));
        mx = fmaxf(mx, __shfl_xor(mx, 2));
        mx = fmaxf(mx, __shfl_xor(mx, 4));
        mx = fmaxf(mx, __shfl_xor(mx, 8));
        float mnew = fmaxf(mrun[r], mx);
        fac[r] = __expf(mrun[r] - mnew);
        mrun[r] = mnew;
        float ps = 0.f;
#pragma unroll
        for (int ct = 0; ct < 4; ++ct) {
          float pv = __expf(sac[ct][r] - mnew);
          p[ct][r] = pv;
          ps += pv;
        }
        ps += __shfl_xor(ps, 1);
        ps += __shfl_xor(ps, 2);
        ps += __shfl_xor(ps, 4);
        ps += __shfl_xor(ps, 8);
        lrun[r] = lrun[r] * fac[r] + ps;
      }
    } else {  // diagonal tile: causal mask
      int s0 = it * 64;
#pragma unroll
      for (int r = 0; r < 4; ++r) {
        int tg = qt * 64 + w * 16 + l4 * 4 + r;
        float mx = -__builtin_inff();
#pragma unroll
        for (int ct = 0; ct < 4; ++ct) {
          int sg = s0 + ct * 16 + l15;
          float sv = (sg <= tg) ? sac[ct][r] : -__builtin_inff();
          mx = fmaxf(mx, sv);
        }
        mx = fmaxf(mx, __shfl_xor(mx, 1));
        mx = fmaxf(mx, __shfl_xor(mx, 2));
        mx = fmaxf(mx, __shfl_xor(mx, 4));
        mx = fmaxf(mx, __shfl_xor(mx, 8));
        float mnew = fmaxf(mrun[r], mx);
        fac[r] = __expf(mrun[r] - mnew);
        mrun[r] = mnew;
        float ps = 0.f;
#pragma unroll
        for (int ct = 0; ct < 4; ++ct) {
          int sg = s0 + ct * 16 + l15;
          float pv = (sg <= tg) ? __expf(sac[ct][r] - mnew) : 0.f;
          p[ct][r] = pv;
          ps += pv;
        }
        ps += __shfl_xor(ps, 1);
        ps += __shfl_xor(ps, 2);
        ps += __shfl_xor(ps, 4);
        ps += __shfl_xor(ps, 8);
        lrun[r] = lrun[r] * fac[r] + ps;
      }
    }
#pragma unroll
    for (int c = 0; c < 8; ++c)
#pragma unroll
      for (int r = 0; r < 4; ++r) occ[c][r] *= fac[r];
    // P (D-layout) -> LDS (swizzled rows) -> A-layout for PV
#pragma unroll
    for (int ct = 0; ct < 4; ++ct)
#pragma unroll
      for (int r = 0; r < 4; ++r) {
        int prow = l4 * 4 + r, pcol = ct * 16 + l15;
        unsigned pby = (unsigned)((prow << 7) + (pcol << 1));
        *(u16*)((char*)&Pl[w][0] + (pby ^ ((prow & 7) << 4))) = f2b(p[ct][r]);
      }
    // cross-lane LDS RAW within the wave: drain LDS queue before reading P
    asm volatile("s_waitcnt lgkmcnt(0)" ::: "memory");
    __builtin_amdgcn_sched_barrier(0);
    __builtin_amdgcn_s_setprio(1);
#pragma unroll
    for (int kc2 = 0; kc2 < 2; ++kc2) {
      unsigned rby = (unsigned)((l15 << 7) + (kc2 << 6) + (l4 << 4));
      bf8_t pf = *(const bf8_t*)((const char*)&Pl[w][0] + (rby ^ ((l15 & 7) << 4)));
#pragma unroll
      for (int c = 0; c < 8; ++c) {
        int drow = c * 16 + l15;
        bf8_t vf = *(const bf8_t*)((const char*)Vl +
                   (((drow << 7) + (kc2 << 6) + (l4 << 4)) ^ ((drow & 7) << 4)));
        occ[c] = mfma16(pf, vf, occ[c]);
      }
    }
    __builtin_amdgcn_s_setprio(0);
    __syncthreads();
  }
  // epilogue: O /= l, write bf16 (B*T, H*D)
  float inv[4];
#pragma unroll
  for (int r = 0; r < 4; ++r) inv[r] = 1.f / lrun[r];
  int orow0 = qt * 64 + w * 16 + l4 * 4;
#pragma unroll
  for (int c = 0; c < 8; ++c) {
    int col = h * cD + c * 16 + l15;
#pragma unroll
    for (int r = 0; r < 4; ++r)
      obuf[(size_t)(b * cT + orow0 + r) * (cH * cD) + col] = f2b(occ[c][r] * inv[r]);
  }
}

// ---------------- launch ----------------

extern "C" void kernel_launch(void* const* d_in, const int* in_sizes, int n_in,
                              void* d_out, int out_size, void* d_ws, size_t ws_size,
                              hipStream_t stream) {
  (void)in_sizes; (void)n_in; (void)out_size; (void)ws_size;
  const float* x  = (const float*)d_in[0];
  const float* Wq = (const float*)d_in[1];
  const float* Wk = (const float*)d_in[2];
  const float* Wv = (const float*)d_in[3];
  const float* Wo = (const float*)d_in[4];

  char* p = (char*)d_ws;
  u16* xb   = (u16*)p;  p += (size_t)cBT * cC * 2;        // 16.8 MB (reused as ob)
  u16* wt   = (u16*)p;  p += (size_t)cNQKV * cC * 2;      // 12.6 MB (Wqkv^T)
  u16* wot  = (u16*)p;  p += (size_t)cC * cC * 2;         // 8.4 MB  (Wo^T)
  u16* qkv  = (u16*)p;  p += (size_t)cBT * cNQKV * 2;     // 25.2 MB
  u16* vt   = (u16*)p;  p += (size_t)cB * cKV * cD * cT * 2; // 4.2 MB
  float* cosb = (float*)p; p += (size_t)cT * 64 * 4;      // 0.5 MB
  float* sinb = (float*)p; p += (size_t)cT * 64 * 4;      // 0.5 MB
  u16* ob = xb;  // xb dead after QKV GEMM; ob born in k_attn — lifetimes disjoint

  k_cvt_x<<<dim3(cBT * cC / 1024), 256, 0, stream>>>(x, xb);
  k_tconv<<<dim3(cNQKV / 64, cC / 64), 256, 0, stream>>>(
      Wq, cH * cD, cH * cD, Wk, cKV * cD, cH * cD + cKV * cD, Wv, cKV * cD, wt, cC);
  k_tconv<<<dim3(cC / 64, cC / 64), 256, 0, stream>>>(
      Wo, cC, cC, Wo, cC, cC, Wo, cC, wot, cC);
  k_ropetab<<<dim3(cT * 64 / 256), 256, 0, stream>>>(cosb, sinb);
  k_gemm256<cNQKV, false><<<dim3(cNQKV / 256, cBT / 128), 512, 0, stream>>>(xb, wt, qkv);
  k_rope<<<dim3(cBT * 320 / 256), 256, 0, stream>>>(qkv, cosb, sinb);
  k_vtrans<<<dim3(cT / 64, cD / 64, cB * cKV), 256, 0, stream>>>(qkv, vt);
  // LPT: x = (b,h) fast, y = descending qt (longest blocks dispatch first)
  k_attn<<<dim3(cB * cH, cT / 64), 256, 0, stream>>>(qkv, vt, ob);
  k_gemm256<cC, true><<<dim3(cC / 256, cBT / 128), 512, 0, stream>>>(ob, wot, d_out);
}

// Round 9
// 313.616 us; speedup vs baseline: 1.0532x; 1.0364x over previous
//
#include <hip/hip_runtime.h>
#include <hip/hip_bf16.h>

// GQA block: x@Wqkv -> RoPE -> causal GQA attention -> @Wo
// B=2 T=2048 C=2048 H=16 KV=4 D=128, fp32 in/out, bf16 MFMA internally.

typedef unsigned short u16;
typedef __attribute__((ext_vector_type(8))) short   bf8_t;  // 8 bf16 (MFMA A/B frag)
typedef __attribute__((ext_vector_type(4))) float   f4_t;   // MFMA C/D frag
typedef __attribute__((ext_vector_type(4))) int     i4_t;   // 16B staging reg
typedef __attribute__((ext_vector_type(4))) u16     u16x4;

static constexpr int cB = 2, cT = 2048, cC = 2048, cH = 16, cKV = 4, cD = 128;
static constexpr int cBT = cB * cT;              // 4096 rows
static constexpr int cNQKV = cH*cD + 2*cKV*cD;   // 3072 (Q|K|V)
static constexpr int cKOFF = cH*cD;              // 2048
static constexpr int cVOFF = cH*cD + cKV*cD;     // 2560
static constexpr float cQSCALE = 0.08838834764831843f; // 1/sqrt(128)

#define DEVI __device__ __forceinline__

// global_load_lds address-space casts, via integers (always-legal casts):
// generic->AS1 is numerically identity; generic LDS ptr's low 32 bits = LDS
// byte offset. readfirstlane puts LDS base in SGPR (CK amd_direct_load).
#define AS1G(p) ((const __attribute__((address_space(1))) void*)(unsigned long long)(p))
#define AS3I(x) ((__attribute__((address_space(3))) void*)(unsigned)(x))

DEVI u16 f2b(float f) {           // fp32 -> bf16 RNE
  union { float f; unsigned u; } v; v.f = f;
  unsigned r = v.u + 0x7FFFu + ((v.u >> 16) & 1u);
  return (u16)(r >> 16);
}
DEVI float b2f(u16 h) {
  union { unsigned u; float f; } v; v.u = ((unsigned)h) << 16; return v.f;
}
DEVI f4_t mfma16(bf8_t a, bf8_t b, f4_t c) {
  return __builtin_amdgcn_mfma_f32_16x16x32_bf16(a, b, c, 0, 0, 0);
}

// ---------------- glue kernels ----------------

__global__ void k_cvt_x(const float* __restrict__ x, u16* __restrict__ xb) {
  int i = (blockIdx.x * 256 + threadIdx.x) * 4;
  float4 v = *(const float4*)(x + i);
  u16x4 o; o.x = f2b(v.x); o.y = f2b(v.y); o.z = f2b(v.z); o.w = f2b(v.w);
  *(u16x4*)(xb + i) = o;
}

// dst[n][k] = src(k, n) as bf16; src split across up to 3 arrays along n.
__global__ void k_tconv(const float* __restrict__ s0, int ld0, int ncut0,
                        const float* __restrict__ s1, int ld1, int ncut1,
                        const float* __restrict__ s2, int ld2,
                        u16* __restrict__ dst, int Kdim) {
  __shared__ float tile[64][65];
  int n0 = blockIdx.x * 64, k0 = blockIdx.y * 64;
  int tid = threadIdx.x;
#pragma unroll
  for (int r = 0; r < 16; ++r) {
    int idx = r * 256 + tid;
    int kk = idx >> 6, nn = idx & 63;
    int n = n0 + nn;
    float v;
    if (n < ncut0)      v = s0[(size_t)(k0 + kk) * ld0 + n];
    else if (n < ncut1) v = s1[(size_t)(k0 + kk) * ld1 + (n - ncut0)];
    else                v = s2[(size_t)(k0 + kk) * ld2 + (n - ncut1)];
    tile[kk][nn] = v;
  }
  __syncthreads();
#pragma unroll
  for (int r = 0; r < 16; ++r) {
    int idx = r * 256 + tid;
    int nn = idx >> 6, kk = idx & 63;
    dst[(size_t)(n0 + nn) * Kdim + k0 + kk] = f2b(tile[kk][nn]);
  }
}

__global__ void k_ropetab(float* __restrict__ cosb, float* __restrict__ sinb) {
  int i = blockIdx.x * 256 + threadIdx.x;  // T*64
  int t = i >> 6, d = i & 63;
  float th = powf(10000.f, -(float)d / 64.f);
  float f = (float)t * th;
  cosb[i] = cosf(f);
  sinb[i] = sinf(f);
}

// in-place RoPE on bf16 qkv rows; heads 0..15 = Q (also *scale), 16..19 = K.
__global__ void k_rope(u16* __restrict__ qkv, const float* __restrict__ cosb,
                       const float* __restrict__ sinb) {
  int i = blockIdx.x * 256 + threadIdx.x;      // BT * 20 heads * 16 quads
  int row = i / 320, p = i - row * 320;
  int head = p >> 4, d4 = (p & 15) << 2;       // d = d4 .. d4+3 (of 64)
  int t = row & (cT - 1);
  u16* base = qkv + (size_t)row * cNQKV + head * cD + d4;
  u16x4 lo4 = *(u16x4*)base;
  u16x4 hi4 = *(u16x4*)(base + 64);
  float4 cv = *(const float4*)(cosb + (t << 6) + d4);
  float4 sv = *(const float4*)(sinb + (t << 6) + d4);
  float sc = (head < cH) ? cQSCALE : 1.f;
  u16x4 olo, ohi;
#pragma unroll
  for (int j = 0; j < 4; ++j) {
    float lo = b2f(lo4[j]), hi = b2f(hi4[j]);
    float c = (&cv.x)[j], s = (&sv.x)[j];
    olo[j] = f2b((lo * c - hi * s) * sc);
    ohi[j] = f2b((hi * c + lo * s) * sc);
  }
  *(u16x4*)base = olo;
  *(u16x4*)(base + 64) = ohi;
}

// vt[b,g,d,t] = V[b,t,g,d]  (64x64 LDS tile transpose)
__global__ void k_vtrans(const u16* __restrict__ qkv, u16* __restrict__ vt) {
  __shared__ u16 tile[64][65];
  int s0 = blockIdx.x * 64, d0 = blockIdx.y * 64, bg = blockIdx.z;
  int b = bg >> 2, g = bg & 3;
  int tid = threadIdx.x;
#pragma unroll
  for (int r = 0; r < 16; ++r) {
    int idx = r * 256 + tid;
    int ss = idx >> 6, dd = idx & 63;
    tile[ss][dd] = qkv[(size_t)(b * cT + s0 + ss) * cNQKV + cVOFF + g * cD + d0 + dd];
  }
  __syncthreads();
#pragma unroll
  for (int r = 0; r < 16; ++r) {
    int idx = r * 256 + tid;
    int dd = idx >> 6, ss = idx & 63;
    vt[(size_t)((b * cKV + g) * cD + d0 + dd) * cT + s0 + ss] = tile[ss][dd];
  }
}

// ---------------- GEMM: C(M x N_) = A(M x K) * Bt(N_ x K)^T ----------------
// 128x256 tile, BK=32, 8 waves (2x4), ring of 3 LDS slots (72 KB -> 2
// blocks/CU so QKV's 384 blocks are ALL resident in one round; R8's 4-slot
// 96 KB forced 1 block/CU = 1.5 dispatch rounds on QKV), counted vmcnt:
// one raw s_barrier + vmcnt(3) per K-step (drain only on last iter).
// Slot layout: A[128 rows x 64B] @ +0, B[256 rows x 64B] @ +8192; row's four
// 16B k-slots XOR-swizzled by ((row>>1)&3)<<4 on BOTH global source and LDS
// read (involution; gload_lds dest stays linear: byte = chunk*16).
// Safety: tile kt+2 -> slot of tile kt-1, whose readers finished before
// barrier(kt): each wave's iter-(kt-1) ds_reads complete before its MFMAs
// issue (compiler lgkmcnt), MFMAs precede barrier(kt); staging is pinned
// after the barrier by sched_barrier(0). vmcnt(3)+barrier => tile kt
// resident for all waves before its reads.
template <int NBLK, bool OUTF32>
__global__ __launch_bounds__(512, 4) void k_gemm256(const u16* __restrict__ A,
                                                    const u16* __restrict__ Bt,
                                                    void* __restrict__ Cout) {
  constexpr int K_ = 2048, NT = K_ / 32;
  constexpr unsigned SLOT = 24576u, SLOT2 = 49152u;
  __shared__ __align__(16) u16 lds[3 * 12288];   // 3 slots x 24576 B = 72 KB
  const int tid = threadIdx.x;
  const int l = tid & 63, wid = tid >> 6;
  const int l15 = l & 15, l4 = l >> 4;
  const int wr = wid >> 2, wc = wid & 3;         // wave tile: rows wr*64, cols wc*64
  const int m0 = blockIdx.y * 128, n0 = blockIdx.x * 256;

  // staging source: chunk tid -> row tid>>2, k-slot tid&3 (source pre-swizzled)
  const int rowS = tid >> 2, slotS = tid & 3;
  const int colS = (slotS * 16) ^ (((rowS >> 1) & 3) << 4);
  const char* aG  = (const char*)A  + ((size_t)(m0 + rowS) * K_) * 2 + colS;
  const char* bG0 = (const char*)Bt + ((size_t)(n0 + rowS) * K_) * 2 + colS;
  const char* bG1 = (const char*)Bt + ((size_t)(n0 + 128 + rowS) * K_) * 2 + colS;
  // ((rowS+128)>>1)&3 == (rowS>>1)&3, so bG1 shares colS.

  // wave-uniform LDS dest bases (lane*16 added by HW)
  const unsigned ldsB = (unsigned)(unsigned long long)(const char*)lds;
  const unsigned aDst  = __builtin_amdgcn_readfirstlane(ldsB + (unsigned)wid * 1024u);
  const unsigned bDst0 = __builtin_amdgcn_readfirstlane(ldsB + 8192u + (unsigned)wid * 1024u);
  const unsigned bDst1 = __builtin_amdgcn_readfirstlane(ldsB + 16384u + (unsigned)wid * 1024u);

#define G_STAGE(kt_, sb_) { \
    __builtin_amdgcn_global_load_lds(AS1G(aG  + (size_t)(kt_) * 64), AS3I(aDst  + (sb_)), 16, 0, 0); \
    __builtin_amdgcn_global_load_lds(AS1G(bG0 + (size_t)(kt_) * 64), AS3I(bDst0 + (sb_)), 16, 0, 0); \
    __builtin_amdgcn_global_load_lds(AS1G(bG1 + (size_t)(kt_) * 64), AS3I(bDst1 + (sb_)), 16, 0, 0); }

  f4_t acc[4][4];
  f4_t zf = {0.f, 0.f, 0.f, 0.f};
#pragma unroll
  for (int m = 0; m < 4; ++m)
#pragma unroll
    for (int n = 0; n < 4; ++n) acc[m][n] = zf;

  // prologue: 2 tiles in flight (6 loads/thread)
  G_STAGE(0, 0u); G_STAGE(1, SLOT);

  unsigned csb = 0, ssb = SLOT2;   // compute slot of kt; stage slot of kt+2
  for (int kt = 0; kt < NT; ++kt) {
    // tile kt resident (3 loads of kt+1 may stay in flight); drain at tail.
    if (kt < NT - 1) asm volatile("s_waitcnt vmcnt(3)" ::: "memory");
    else             asm volatile("s_waitcnt vmcnt(0)" ::: "memory");
    __builtin_amdgcn_s_barrier();        // all waves' tile-kt chunks resident
    __builtin_amdgcn_sched_barrier(0);   // pin staging below the barrier
    if (kt + 2 < NT) G_STAGE(kt + 2, ssb);

    bf8_t af[4], bf[4];
#pragma unroll
    for (int m = 0; m < 4; ++m) {
      int row = wr * 64 + m * 16 + l15;
      af[m] = *(const bf8_t*)((const char*)lds + csb + row * 64 +
                              ((l4 * 16) ^ (((row >> 1) & 3) << 4)));
    }
#pragma unroll
    for (int n = 0; n < 4; ++n) {
      int row = wc * 64 + n * 16 + l15;
      bf[n] = *(const bf8_t*)((const char*)lds + csb + 8192 + row * 64 +
                              ((l4 * 16) ^ (((row >> 1) & 3) << 4)));
    }
#pragma unroll
    for (int m = 0; m < 4; ++m)
#pragma unroll
      for (int n = 0; n < 4; ++n)
        acc[m][n] = mfma16(af[m], bf[n], acc[m][n]);

    csb = (csb == SLOT2) ? 0u : csb + SLOT;
    ssb = (ssb == SLOT2) ? 0u : ssb + SLOT;
  }
#undef G_STAGE
  // epilogue: D row=(l>>4)*4+r, col=l&15  [m89-verified]
#pragma unroll
  for (int m = 0; m < 4; ++m) {
#pragma unroll
    for (int n = 0; n < 4; ++n) {
      int col = n0 + wc * 64 + n * 16 + l15;
#pragma unroll
      for (int r = 0; r < 4; ++r) {
        int row = m0 + wr * 64 + m * 16 + l4 * 4 + r;
        if (OUTF32)
          ((float*)Cout)[(size_t)row * NBLK + col] = acc[m][n][r];
        else
          ((u16*)Cout)[(size_t)row * NBLK + col] = f2b(acc[m][n][r]);
      }
    }
  }
}

// ---------------- fused causal GQA attention ----------------
// LPT dispatch: qt = 31 - blockIdx.y (longest first, short blocks backfill).
// 3 blocks/CU resident. 4 waves x 16 q-rows; KV tiles of 64. K/V/P LDS
// XOR-swizzled (byte ^= (row&7)<<4) per G4. Banked at ~104 us (R5-R8).
__global__ __launch_bounds__(256) void k_attn(const u16* __restrict__ qkv,
                                              const u16* __restrict__ vt,
                                              u16* __restrict__ obuf) {
  __shared__ __align__(16) u16 Kl[64 * 128];
  __shared__ __align__(16) u16 Vl[128 * 64];
  __shared__ __align__(16) u16 Pl[4][16 * 64];  // per-wave P buffer, swizzled

  int bh = blockIdx.x;               // fast dim: all (b,h) at one qt-level
  int qt = 31 - (int)blockIdx.y;     // slow dim: descending work (LPT)
  int b = bh >> 4, h = bh & 15;
  int g = h >> 2;  // kv head (R=4)
  int tid = threadIdx.x;
  int l = tid & 63, w = tid >> 6;
  int l15 = l & 15, l4 = l >> 4;

  const char* qkvB = (const char*)qkv;
  const char* vtB  = (const char*)vt;
  const size_t kRowBase = ((size_t)(b * cT) * cNQKV + cKOFF + g * cD) * 2;
  const size_t vRowBase = ((size_t)((b * cKV + g) * cD)) * cT * 2;
  f4_t zf = {0.f, 0.f, 0.f, 0.f};

  // Q fragments in registers (A-operand: row=l&15, k=(l>>4)*8+j)
  int trow = qt * 64 + w * 16 + l15;
  const u16* qrow = qkv + (size_t)(b * cT + trow) * cNQKV + h * cD;
  bf8_t qf[4];
#pragma unroll
  for (int kc = 0; kc < 4; ++kc) qf[kc] = *(const bf8_t*)(qrow + kc * 32 + l4 * 8);

  f4_t occ[8];
#pragma unroll
  for (int c = 0; c < 8; ++c) occ[c] = zf;
  float mrun[4], lrun[4];
#pragma unroll
  for (int r = 0; r < 4; ++r) { mrun[r] = -__builtin_inff(); lrun[r] = 0.f; }

  i4_t kreg[4], vreg[4];
#pragma unroll
  for (int rr = 0; rr < 4; ++rr) {  // prologue: tile 0 -> regs
    int off = tid * 16 + rr * 4096;
    int s = off >> 8, dby = off & 255;
    kreg[rr] = *(const i4_t*)(qkvB + kRowBase + (size_t)s * (cNQKV * 2) + dby);
    int dv = off >> 7, sby = off & 127;
    vreg[rr] = *(const i4_t*)(vtB + vRowBase + (size_t)dv * (cT * 2) + sby);
  }

  int nt = qt + 1;  // causal tile bound
  for (int it = 0; it < nt; ++it) {
#pragma unroll
    for (int rr = 0; rr < 4; ++rr) {  // regs -> LDS (swizzled)
      int off = tid * 16 + rr * 4096;
      int s = off >> 8, dby = off & 255;
      *(i4_t*)((char*)Kl + (((s << 8) + dby) ^ ((s & 7) << 4))) = kreg[rr];
      int dv = off >> 7, sby = off & 127;
      *(i4_t*)((char*)Vl + (((dv << 7) + sby) ^ ((dv & 7) << 4))) = vreg[rr];
    }
    __syncthreads();
    if (it + 1 < nt) {  // prefetch next tile into regs (hidden under MFMA)
      int s0n = (it + 1) * 64;
#pragma unroll
      for (int rr = 0; rr < 4; ++rr) {
        int off = tid * 16 + rr * 4096;
        int s = off >> 8, dby = off & 255;
        kreg[rr] = *(const i4_t*)(qkvB + kRowBase + (size_t)(s0n + s) * (cNQKV * 2) + dby);
        int dv = off >> 7, sby = off & 127;
        vreg[rr] = *(const i4_t*)(vtB + vRowBase + (size_t)dv * (cT * 2) + (size_t)s0n * 2 + sby);
      }
    }
    // S = Q K^T  (16 q-rows x 64 kv-cols per wave)
    f4_t sac[4];
#pragma unroll
    for (int ct = 0; ct < 4; ++ct) sac[ct] = zf;
    __builtin_amdgcn_s_setprio(1);
#pragma unroll
    for (int ct = 0; ct < 4; ++ct) {
      int srow = ct * 16 + l15;
#pragma unroll
      for (int kc = 0; kc < 4; ++kc) {
        bf8_t kf = *(const bf8_t*)((const char*)Kl +
                   (((srow << 8) + (kc << 6) + (l4 << 4)) ^ ((srow & 7) << 4)));
        sac[ct] = mfma16(qf[kc], kf, sac[ct]);
      }
    }
    __builtin_amdgcn_s_setprio(0);
    // online softmax; lane holds rows l4*4+r, cols ct*16+l15.
    float p[4][4], fac[4];
    if (it < qt) {  // full tile, no mask
#pragma unroll
      for (int r = 0; r < 4; ++r) {
        float mx = fmaxf(fmaxf(sac[0][r], sac[1][r]), fmaxf(sac[2][r], sac[3][r]));
        mx = fmaxf(mx, __shfl_xor(mx, 1));
        mx = fmaxf(mx, __shfl_xor(mx, 2));
        mx = fmaxf(mx, __shfl_xor(mx, 4));
        mx = fmaxf(mx, __shfl_xor(mx, 8));
        float mnew = fmaxf(mrun[r], mx);
        fac[r] = __expf(mrun[r] - mnew);
        mrun[r] = mnew;
        float ps = 0.f;
#pragma unroll
        for (int ct = 0; ct < 4; ++ct) {
          float pv = __expf(sac[ct][r] - mnew);
          p[ct][r] = pv;
          ps += pv;
        }
        ps += __shfl_xor(ps, 1);
        ps += __shfl_xor(ps, 2);
        ps += __shfl_xor(ps, 4);
        ps += __shfl_xor(ps, 8);
        lrun[r] = lrun[r] * fac[r] + ps;
      }
    } else {  // diagonal tile: causal mask
      int s0 = it * 64;
#pragma unroll
      for (int r = 0; r < 4; ++r) {
        int tg = qt * 64 + w * 16 + l4 * 4 + r;
        float mx = -__builtin_inff();
#pragma unroll
        for (int ct = 0; ct < 4; ++ct) {
          int sg = s0 + ct * 16 + l15;
          float sv = (sg <= tg) ? sac[ct][r] : -__builtin_inff();
          mx = fmaxf(mx, sv);
        }
        mx = fmaxf(mx, __shfl_xor(mx, 1));
        mx = fmaxf(mx, __shfl_xor(mx, 2));
        mx = fmaxf(mx, __shfl_xor(mx, 4));
        mx = fmaxf(mx, __shfl_xor(mx, 8));
        float mnew = fmaxf(mrun[r], mx);
        fac[r] = __expf(mrun[r] - mnew);
        mrun[r] = mnew;
        float ps = 0.f;
#pragma unroll
        for (int ct = 0; ct < 4; ++ct) {
          int sg = s0 + ct * 16 + l15;
          float pv = (sg <= tg) ? __expf(sac[ct][r] - mnew) : 0.f;
          p[ct][r] = pv;
          ps += pv;
        }
        ps += __shfl_xor(ps, 1);
        ps += __shfl_xor(ps, 2);
        ps += __shfl_xor(ps, 4);
        ps += __shfl_xor(ps, 8);
        lrun[r] = lrun[r] * fac[r] + ps;
      }
    }
#pragma unroll
    for (int c = 0; c < 8; ++c)
#pragma unroll
      for (int r = 0; r < 4; ++r) occ[c][r] *= fac[r];
    // P (D-layout) -> LDS (swizzled rows) -> A-layout for PV
#pragma unroll
    for (int ct = 0; ct < 4; ++ct)
#pragma unroll
      for (int r = 0; r < 4; ++r) {
        int prow = l4 * 4 + r, pcol = ct * 16 + l15;
        unsigned pby = (unsigned)((prow << 7) + (pcol << 1));
        *(u16*)((char*)&Pl[w][0] + (pby ^ ((prow & 7) << 4))) = f2b(p[ct][r]);
      }
    // cross-lane LDS RAW within the wave: drain LDS queue before reading P
    asm volatile("s_waitcnt lgkmcnt(0)" ::: "memory");
    __builtin_amdgcn_sched_barrier(0);
    __builtin_amdgcn_s_setprio(1);
#pragma unroll
    for (int kc2 = 0; kc2 < 2; ++kc2) {
      unsigned rby = (unsigned)((l15 << 7) + (kc2 << 6) + (l4 << 4));
      bf8_t pf = *(const bf8_t*)((const char*)&Pl[w][0] + (rby ^ ((l15 & 7) << 4)));
#pragma unroll
      for (int c = 0; c < 8; ++c) {
        int drow = c * 16 + l15;
        bf8_t vf = *(const bf8_t*)((const char*)Vl +
                   (((drow << 7) + (kc2 << 6) + (l4 << 4)) ^ ((drow & 7) << 4)));
        occ[c] = mfma16(pf, vf, occ[c]);
      }
    }
    __builtin_amdgcn_s_setprio(0);
    __syncthreads();
  }
  // epilogue: O /= l, write bf16 (B*T, H*D)
  float inv[4];
#pragma unroll
  for (int r = 0; r < 4; ++r) inv[r] = 1.f / lrun[r];
  int orow0 = qt * 64 + w * 16 + l4 * 4;
#pragma unroll
  for (int c = 0; c < 8; ++c) {
    int col = h * cD + c * 16 + l15;
#pragma unroll
    for (int r = 0; r < 4; ++r)
      obuf[(size_t)(b * cT + orow0 + r) * (cH * cD) + col] = f2b(occ[c][r] * inv[r]);
  }
}

// ---------------- launch ----------------

extern "C" void kernel_launch(void* const* d_in, const int* in_sizes, int n_in,
                              void* d_out, int out_size, void* d_ws, size_t ws_size,
                              hipStream_t stream) {
  (void)in_sizes; (void)n_in; (void)out_size; (void)ws_size;
  const float* x  = (const float*)d_in[0];
  const float* Wq = (const float*)d_in[1];
  const float* Wk = (const float*)d_in[2];
  const float* Wv = (const float*)d_in[3];
  const float* Wo = (const float*)d_in[4];

  char* p = (char*)d_ws;
  u16* xb   = (u16*)p;  p += (size_t)cBT * cC * 2;        // 16.8 MB (reused as ob)
  u16* wt   = (u16*)p;  p += (size_t)cNQKV * cC * 2;      // 12.6 MB (Wqkv^T)
  u16* wot  = (u16*)p;  p += (size_t)cC * cC * 2;         // 8.4 MB  (Wo^T)
  u16* qkv  = (u16*)p;  p += (size_t)cBT * cNQKV * 2;     // 25.2 MB
  u16* vt   = (u16*)p;  p += (size_t)cB * cKV * cD * cT * 2; // 4.2 MB
  float* cosb = (float*)p; p += (size_t)cT * 64 * 4;      // 0.5 MB
  float* sinb = (float*)p; p += (size_t)cT * 64 * 4;      // 0.5 MB
  u16* ob = xb;  // xb dead after QKV GEMM; ob born in k_attn — lifetimes disjoint

  k_cvt_x<<<dim3(cBT * cC / 1024), 256, 0, stream>>>(x, xb);
  k_tconv<<<dim3(cNQKV / 64, cC / 64), 256, 0, stream>>>(
      Wq, cH * cD, cH * cD, Wk, cKV * cD, cH * cD + cKV * cD, Wv, cKV * cD, wt, cC);
  k_tconv<<<dim3(cC / 64, cC / 64), 256, 0, stream>>>(
      Wo, cC, cC, Wo, cC, cC, Wo, cC, wot, cC);
  k_ropetab<<<dim3(cT * 64 / 256), 256, 0, stream>>>(cosb, sinb);
  k_gemm256<cNQKV, false><<<dim3(cNQKV / 256, cBT / 128), 512, 0, stream>>>(xb, wt, qkv);
  k_rope<<<dim3(cBT * 320 / 256), 256, 0, stream>>>(qkv, cosb, sinb);
  k_vtrans<<<dim3(cT / 64, cD / 64, cB * cKV), 256, 0, stream>>>(qkv, vt);
  // LPT: x = (b,h) fast, y = descending qt (longest blocks dispatch first)
  k_attn<<<dim3(cB * cH, cT / 64), 256, 0, stream>>>(qkv, vt, ob);
  k_gemm256<cC, true><<<dim3(cC / 256, cBT / 128), 512, 0, stream>>>(ob, wot, d_out);
}